// Round 5
// baseline (571.710 us; speedup 1.0000x reference)
//
#include <hip/hip_runtime.h>
#include <hip/hip_bf16.h>

// Problem constants (from reference)
constexpr int N_NODES = 50000;
constexpr int N_EDGES = 600000;
constexpr int ND = 128;   // NODE_DIM
constexpr int ED = 64;    // EDGE_DIM
constexpr int MD = 128;   // MSG_DIM
constexpr int H1 = 32;    // edge MLP hidden
constexpr int H2 = 64;    // node MLP hidden

typedef __attribute__((ext_vector_type(8))) short short8;   // 8 bf16 (4 VGPRs)
typedef __attribute__((ext_vector_type(4))) float f32x4;    // MFMA acc
typedef __attribute__((ext_vector_type(4))) unsigned int uint32x4;

#define MFMA16(a, b, c) __builtin_amdgcn_mfma_f32_16x16x32_bf16((a), (b), (c), 0, 0, 0)

// ---------------- workspace layout (bytes) ----------------
constexpr int COUNTS_PAD = 53248;   // 1024*52 (scan CHUNK=52, int4 loads)
constexpr int WCTR_IDX   = 51200;   // spare zeroed int in counts region: work counter
constexpr size_t WS_MSGS    = 0;                                        // E*128 bf16
constexpr size_t WS_PRE     = WS_MSGS + (size_t)N_EDGES * MD * 2;       // N*128 bf16 (a1|a2|a3)
constexpr size_t WS_POS     = WS_PRE + (size_t)N_NODES * 128 * 2;       // E int
constexpr size_t WS_COUNTS  = WS_POS + (size_t)N_EDGES * 4;             // COUNTS_PAD int
constexpr size_t WS_OFFSETS = WS_COUNTS + (size_t)COUNTS_PAD * 4;       // N+1 int
constexpr size_t WS_WFE     = ((WS_OFFSETS + (size_t)(N_NODES + 1) * 4 + 15) / 16) * 16;
constexpr size_t WS_WFN     = WS_WFE + (size_t)44 * 64 * 16;            // 44 edge frags
constexpr size_t WS_END     = WS_WFN + (size_t)32 * 64 * 16;            // 32 node frags

__device__ inline float bflo(unsigned u) { return __uint_as_float(u << 16); }
__device__ inline float bfhi(unsigned u) { return __uint_as_float(u & 0xffff0000u); }
__device__ inline short f2bf(float f) {
    __hip_bfloat16 h = __float2bfloat16(f);
    return *reinterpret_cast<short*>(&h);
}
// packed f32 pair -> bf16 pair (1 instr)
__device__ inline unsigned pkbf(float a, float b) {
    unsigned r;
    asm("v_cvt_pk_bf16_f32 %0, %1, %2" : "=v"(r) : "v"(a), "v"(b));
    return r;
}
__device__ inline unsigned prelu(float a, float b) {
    return pkbf(fmaxf(a, 0.0f), fmaxf(b, 0.0f));
}
__device__ inline short8 pack8(unsigned w0, unsigned w1, unsigned w2, unsigned w3) {
    uint32x4 t{w0, w1, w2, w3};
    return __builtin_bit_cast(short8, t);
}

// Hidden-dim relabeling for swapped-operand layer chaining:
// layer i's output at lane(q,m16) reg (mt,r) carries h = mt*16 + q*4 + r,
// which slots into next layer's B-operand k = kt*32 + q*8 + j with
// mt = kt*2 + (j>>2), r = j&3. Fold h(k) into the weight row order here.
__device__ inline int hperm(int kt, int kq) {   // kq = quad*8+j in [0,32)
    return (kt * 2 + ((kq >> 2) & 1)) * 16 + ((kq >> 3) & 3) * 4 + (kq & 3);
}

// ---------------- weight fragment prep (once, tiny) ----------------
// All wfE frags are A-operands (lane holds W[k=quad*8+j][m=lane&15] = A[m][k]
// of W^T). Frag ids: We1e=0..3 (kt*2+mt), We2=4..11 (mt), Wn1b=12..27
// (kt*4+mt), Wn2=28..43 (kt*8+mt). We2/Wn1b/Wn2 rows permuted by hperm.
// wfN frag ids: combined 128x128 B = [We1[0:128] | We1[128:256] | Wn1[0:128]] -> kt*8+nt.
__global__ __launch_bounds__(256) void wprep(
    const float* __restrict__ We1, const float* __restrict__ We2,
    const float* __restrict__ Wn1, const float* __restrict__ Wn2,
    short8* __restrict__ wfE, short8* __restrict__ wfN)
{
    const int g = blockIdx.x * 256 + threadIdx.x;   // 0..4863
    const int lane = g & 63;
    const int f = g >> 6;                            // 0..75
    const int m16 = lane & 15, quad = lane >> 4;
    short v[8];
    if (f < 44) {
        #pragma unroll
        for (int j = 0; j < 8; ++j) {
            const int kq = quad * 8 + j;
            float s;
            if (f < 4) {
                const int kt = f >> 1, mt = f & 1;
                s = We1[(size_t)(2 * ND + kt * 32 + kq) * H1 + mt * 16 + m16];
            } else if (f < 12) {
                const int mt = f - 4;
                s = We2[(size_t)hperm(0, kq) * MD + mt * 16 + m16];
            } else if (f < 28) {
                const int ff = f - 12, kt = ff >> 2, mt = ff & 3;
                s = Wn1[(size_t)(ND + hperm(kt, kq)) * H2 + mt * 16 + m16];
            } else {
                const int ff = f - 28, kt = ff >> 3, mt = ff & 7;
                s = Wn2[(size_t)hperm(kt, kq) * MD + mt * 16 + m16];
            }
            v[j] = f2bf(s);
        }
        wfE[g] = short8{v[0], v[1], v[2], v[3], v[4], v[5], v[6], v[7]};
    } else {
        const int ff = f - 44, kt = ff >> 3, nt = ff & 7;
        const int n = nt * 16 + m16;
        #pragma unroll
        for (int j = 0; j < 8; ++j) {
            const int k = kt * 32 + quad * 8 + j;
            float s;
            if (n < 32)      s = We1[(size_t)k * H1 + n];
            else if (n < 64) s = We1[(size_t)(ND + k) * H1 + (n - 32)];
            else             s = Wn1[(size_t)k * H2 + (n - 64)];
            v[j] = f2bf(s);
        }
        wfN[(size_t)(f - 44) * 64 + lane] = short8{v[0], v[1], v[2], v[3], v[4], v[5], v[6], v[7]};
    }
}

// ---------------- CSR: histogram + within-segment position -----------------
__global__ __launch_bounds__(256) void hist_pos(const int* __restrict__ eidx,
                                                int* __restrict__ counts,
                                                int* __restrict__ pos) {
    const int e = blockIdx.x * 256 + threadIdx.x;
    if (e < N_EDGES) pos[e] = atomicAdd(&counts[eidx[N_EDGES + e]], 1);
}

__global__ __launch_bounds__(1024) void scan_kernel(const int* __restrict__ counts,
                                                    int* __restrict__ offsets) {
    constexpr int T = 1024;
    const int tid = threadIdx.x;
    const int base = tid * 52;
    int4 v[13];
    int s = 0;
    const int4* pc = (const int4*)(counts + base);
    #pragma unroll
    for (int i = 0; i < 13; ++i) {
        v[i] = pc[i];
        s += v[i].x + v[i].y + v[i].z + v[i].w;
    }
    __shared__ int sm[T];
    sm[tid] = s;
    __syncthreads();
    for (int off = 1; off < T; off <<= 1) {
        const int t = (tid >= off) ? sm[tid - off] : 0;
        __syncthreads();
        sm[tid] += t;
        __syncthreads();
    }
    int run = sm[tid] - s;
    #pragma unroll
    for (int i = 0; i < 13; ++i) {
        const int idx = base + i * 4;
        if (idx     <= N_NODES) offsets[idx]     = run;  run += v[i].x;
        if (idx + 1 <= N_NODES) offsets[idx + 1] = run;  run += v[i].y;
        if (idx + 2 <= N_NODES) offsets[idx + 2] = run;  run += v[i].z;
        if (idx + 3 <= N_NODES) offsets[idx + 3] = run;  run += v[i].w;
    }
}

// ---------------- node precompute as MFMA GEMM: pre = nf @ [B128x128] -------
__global__ __launch_bounds__(256) void node_pre_mfma(
    const float* __restrict__ nf, const short8* __restrict__ wfN,
    unsigned short* __restrict__ pre)
{
    __shared__ short ost[4][2048];   // per-wave 16x128 out stage
    const int tid = threadIdx.x;
    const int w = tid >> 6, lane = tid & 63;
    const int m16 = lane & 15, quad = lane >> 4;
    const int n0 = blockIdx.x * 64 + w * 16;

    short8 a[4];
    #pragma unroll
    for (int kt = 0; kt < 4; ++kt) {
        const int node = min(n0 + m16, N_NODES - 1);
        const float* pn = nf + (size_t)node * ND + kt * 32 + quad * 8;
        const float4 f0 = *(const float4*)pn;
        const float4 f1 = *(const float4*)(pn + 4);
        a[kt] = pack8(pkbf(f0.x, f0.y), pkbf(f0.z, f0.w),
                      pkbf(f1.x, f1.y), pkbf(f1.z, f1.w));
    }
    f32x4 acc[8];
    #pragma unroll
    for (int nt = 0; nt < 8; ++nt) acc[nt] = f32x4{0.f, 0.f, 0.f, 0.f};
    #pragma unroll
    for (int kt = 0; kt < 4; ++kt) {
        #pragma unroll
        for (int nt = 0; nt < 8; ++nt)
            acc[nt] = MFMA16(a[kt], wfN[(size_t)(kt * 8 + nt) * 64 + lane], acc[nt]);
    }
    short* o = &ost[w][0];
    #pragma unroll
    for (int nt = 0; nt < 8; ++nt)
        #pragma unroll
        for (int r = 0; r < 4; ++r)
            o[(quad * 4 + r) * 128 + nt * 16 + m16] = f2bf(acc[nt][r]);  // no relu
    asm volatile("s_waitcnt lgkmcnt(0)" ::: "memory");
    #pragma unroll
    for (int i = 0; i < 4; ++i) {
        const int row = i * 4 + quad;
        const int node = n0 + row;
        if (node < N_NODES) {
            const uint4 v = ((const uint4*)(o + row * 128))[m16];
            *((uint4*)(pre + (size_t)node * 128) + m16) = v;
        }
    }
}

// ---------------- fused 4-layer edge MLP: persistent, LDS weights -----------
// 768 persistent blocks, 4 independent waves each. Weights (44 frags, 45KB) +
// biases (1.4KB) staged in LDS once per block -> in-loop weight access is
// conflict-free ds_read_b128 instead of 44 L2 round-trips per unit.
// Each WAVE steals 32-edge units (2 MFMA tiles) off a global atomic counter:
// perfect balance, zero in-loop barriers. Gather is per-lane direct (uint2
// slices of pre in exactly the consumer layout - no LDS transpose), and the
// output is stored per-lane direct (8x8B per tile, full 256B row per wave).
__global__ __launch_bounds__(256, 3) void edge_mfma(
    const float* __restrict__ ef, const int* __restrict__ eidx,
    const unsigned short* __restrict__ pre,
    const int* __restrict__ pos, const int* __restrict__ offsets,
    const short8* __restrict__ wfE,
    const float* __restrict__ be1, const float* __restrict__ be2,
    const float* __restrict__ bn1, const float* __restrict__ bn2,
    int* __restrict__ wctr,
    unsigned short* __restrict__ msgs)
{
    constexpr int NUNITS = N_EDGES / 32;   // 18750 units of 32 edges (2 tiles)
    __shared__ short8 wlds[44 * 64];       // 45056 B
    __shared__ float blds[352];            // be1|be2|bn1|bn2 = 1408 B

    const int tid = threadIdx.x;
    // ---- stage weights + biases to LDS (once per block) ----
    for (int i = tid; i < 44 * 64; i += 256) wlds[i] = wfE[i];
    for (int i = tid; i < 352; i += 256) {   // FIX R4: 352 > blockDim, must loop
        float v;
        if (i < 32)       v = be1[i];
        else if (i < 160) v = be2[i - 32];
        else if (i < 224) v = bn1[i - 160];
        else              v = bn2[i - 224];
        blds[i] = v;
    }
    __syncthreads();

    const int lane = tid & 63;
    const int m16 = lane & 15, q = lane >> 4;

    while (true) {
        int u = 0;
        if (lane == 0) u = atomicAdd(wctr, 1);
        u = __shfl(u, 0);
        if (u >= NUNITS) break;

        const int eA = u * 32 + m16;
        const int eB = eA + 16;

        // ---- per-lane direct gather (consumer layout; no LDS transpose) ----
        int src[2], dst[2], slot[2];
        src[0] = eidx[eA];            dst[0] = eidx[N_EDGES + eA];
        src[1] = eidx[eB];            dst[1] = eidx[N_EDGES + eB];
        slot[0] = offsets[dst[0]] + pos[eA];
        slot[1] = offsets[dst[1]] + pos[eB];

        uint2 a1[2][2], a2[2][2], a3[2][4];
        #pragma unroll
        for (int t = 0; t < 2; ++t) {
            const char* ps = (const char*)pre + (size_t)src[t] * 256 + q * 8;
            const char* pd = (const char*)pre + (size_t)dst[t] * 256 + q * 8;
            a1[t][0] = *(const uint2*)(ps);
            a1[t][1] = *(const uint2*)(ps + 32);
            a2[t][0] = *(const uint2*)(pd + 64);
            a2[t][1] = *(const uint2*)(pd + 96);
            a3[t][0] = *(const uint2*)(pd + 128);
            a3[t][1] = *(const uint2*)(pd + 160);
            a3[t][2] = *(const uint2*)(pd + 192);
            a3[t][3] = *(const uint2*)(pd + 224);
        }

        // ---- ef loads (coalesced 8KB per wave-unit) ----
        float4 efv[2][4];
        {
            const float* peA = ef + (size_t)eA * ED + q * 8;
            efv[0][0] = *(const float4*)peA;
            efv[0][1] = *(const float4*)(peA + 4);
            efv[0][2] = *(const float4*)(peA + 32);
            efv[0][3] = *(const float4*)(peA + 36);
            const float* peB = ef + (size_t)eB * ED + q * 8;
            efv[1][0] = *(const float4*)peB;
            efv[1][1] = *(const float4*)(peB + 4);
            efv[1][2] = *(const float4*)(peB + 32);
            efv[1][3] = *(const float4*)(peB + 36);
        }
        short8 aef[2][2];
        #pragma unroll
        for (int t = 0; t < 2; ++t) {
            aef[t][0] = pack8(pkbf(efv[t][0].x, efv[t][0].y), pkbf(efv[t][0].z, efv[t][0].w),
                              pkbf(efv[t][1].x, efv[t][1].y), pkbf(efv[t][1].z, efv[t][1].w));
            aef[t][1] = pack8(pkbf(efv[t][2].x, efv[t][2].y), pkbf(efv[t][2].z, efv[t][2].w),
                              pkbf(efv[t][3].x, efv[t][3].y), pkbf(efv[t][3].z, efv[t][3].w));
        }

        // ---- L1: C[h1=mt*16+q*4+r][edge=m16] = a1+a2+be1 + We1e^T x ef ----
        f32x4 acc1[2][2];
        #pragma unroll
        for (int mt = 0; mt < 2; ++mt) {
            const float4 bb = *(const float4*)&blds[mt * 16 + q * 4];
            #pragma unroll
            for (int t = 0; t < 2; ++t) {
                acc1[t][mt][0] = bflo(a1[t][mt].x) + bflo(a2[t][mt].x) + bb.x;
                acc1[t][mt][1] = bfhi(a1[t][mt].x) + bfhi(a2[t][mt].x) + bb.y;
                acc1[t][mt][2] = bflo(a1[t][mt].y) + bflo(a2[t][mt].y) + bb.z;
                acc1[t][mt][3] = bfhi(a1[t][mt].y) + bfhi(a2[t][mt].y) + bb.w;
            }
        }
        #pragma unroll
        for (int kt = 0; kt < 2; ++kt)
            #pragma unroll
            for (int mt = 0; mt < 2; ++mt) {
                const short8 wf = wlds[(kt * 2 + mt) * 64 + lane];
                acc1[0][mt] = MFMA16(wf, aef[0][kt], acc1[0][mt]);
                acc1[1][mt] = MFMA16(wf, aef[1][kt], acc1[1][mt]);
            }
        short8 b2[2];
        #pragma unroll
        for (int t = 0; t < 2; ++t)
            b2[t] = pack8(prelu(acc1[t][0][0], acc1[t][0][1]), prelu(acc1[t][0][2], acc1[t][0][3]),
                          prelu(acc1[t][1][0], acc1[t][1][1]), prelu(acc1[t][1][2], acc1[t][1][3]));

        // ---- L2: msg(128) = relu(We2^T x h + be2) ----
        f32x4 acc2[2][8];
        #pragma unroll
        for (int mt = 0; mt < 8; ++mt) {
            const float4 bb = *(const float4*)&blds[32 + mt * 16 + q * 4];
            const short8 wf = wlds[(4 + mt) * 64 + lane];
            acc2[0][mt] = f32x4{bb.x, bb.y, bb.z, bb.w};
            acc2[1][mt] = acc2[0][mt];
            acc2[0][mt] = MFMA16(wf, b2[0], acc2[0][mt]);
            acc2[1][mt] = MFMA16(wf, b2[1], acc2[1][mt]);
        }
        short8 b3[2][4];
        #pragma unroll
        for (int t = 0; t < 2; ++t)
            #pragma unroll
            for (int kt = 0; kt < 4; ++kt)
                b3[t][kt] = pack8(prelu(acc2[t][2 * kt][0], acc2[t][2 * kt][1]),
                                  prelu(acc2[t][2 * kt][2], acc2[t][2 * kt][3]),
                                  prelu(acc2[t][2 * kt + 1][0], acc2[t][2 * kt + 1][1]),
                                  prelu(acc2[t][2 * kt + 1][2], acc2[t][2 * kt + 1][3]));

        // ---- L3: h2(64) = relu(a3 + bn1 + Wn1b^T x msg) ----
        f32x4 acc3[2][4];
        #pragma unroll
        for (int mt = 0; mt < 4; ++mt) {
            const float4 bb = *(const float4*)&blds[160 + mt * 16 + q * 4];
            #pragma unroll
            for (int t = 0; t < 2; ++t) {
                acc3[t][mt][0] = bb.x + bflo(a3[t][mt].x);
                acc3[t][mt][1] = bb.y + bfhi(a3[t][mt].x);
                acc3[t][mt][2] = bb.z + bflo(a3[t][mt].y);
                acc3[t][mt][3] = bb.w + bfhi(a3[t][mt].y);
            }
        }
        #pragma unroll
        for (int kt = 0; kt < 4; ++kt)
            #pragma unroll
            for (int mt = 0; mt < 4; ++mt) {
                const short8 wf = wlds[(12 + kt * 4 + mt) * 64 + lane];
                acc3[0][mt] = MFMA16(wf, b3[0][kt], acc3[0][mt]);
                acc3[1][mt] = MFMA16(wf, b3[1][kt], acc3[1][mt]);
            }
        short8 b4[2][2];
        #pragma unroll
        for (int t = 0; t < 2; ++t)
            #pragma unroll
            for (int kt = 0; kt < 2; ++kt)
                b4[t][kt] = pack8(prelu(acc3[t][2 * kt][0], acc3[t][2 * kt][1]),
                                  prelu(acc3[t][2 * kt][2], acc3[t][2 * kt][3]),
                                  prelu(acc3[t][2 * kt + 1][0], acc3[t][2 * kt + 1][1]),
                                  prelu(acc3[t][2 * kt + 1][2], acc3[t][2 * kt + 1][3]));

        // ---- L4: out(128) = relu(Wn2^T x h2 + bn2) ----
        f32x4 acc4[2][8];
        #pragma unroll
        for (int mt = 0; mt < 8; ++mt) {
            const float4 bb = *(const float4*)&blds[224 + mt * 16 + q * 4];
            acc4[0][mt] = f32x4{bb.x, bb.y, bb.z, bb.w};
            acc4[1][mt] = acc4[0][mt];
        }
        #pragma unroll
        for (int kt = 0; kt < 2; ++kt)
            #pragma unroll
            for (int mt = 0; mt < 8; ++mt) {
                const short8 wf = wlds[(28 + kt * 8 + mt) * 64 + lane];
                acc4[0][mt] = MFMA16(wf, b4[0][kt], acc4[0][mt]);
                acc4[1][mt] = MFMA16(wf, b4[1][kt], acc4[1][mt]);
            }

        // ---- per-lane direct store: lane owns out[mt*16+q*4..+3][edge m16] ----
        #pragma unroll
        for (int t = 0; t < 2; ++t) {
            char* pm = (char*)msgs + (size_t)slot[t] * 256 + q * 8;
            #pragma unroll
            for (int mt = 0; mt < 8; ++mt) {
                uint2 wv;
                wv.x = prelu(acc4[t][mt][0], acc4[t][mt][1]);
                wv.y = prelu(acc4[t][mt][2], acc4[t][mt][3]);
                *(uint2*)(pm + mt * 32) = wv;
            }
        }
    }
}

// ---------------- Phase B: per-node streaming sum (msgs CSR-sorted) ---------
// 16 lanes/node, uint4 loads, 4-row unroll with dual accumulator sets (MLP).
__global__ __launch_bounds__(256) void gather2(
    const float* __restrict__ nf,
    const uint4* __restrict__ msgs4,
    const int* __restrict__ offsets,
    float* __restrict__ out)
{
    const int node = blockIdx.x * 16 + (threadIdx.x >> 4);
    const int m16 = threadIdx.x & 15;

    const float4* pn = (const float4*)(nf + (size_t)node * ND) + m16 * 2;
    const float4 n0 = pn[0];
    const float4 n1 = pn[1];

    const int beg = offsets[node];
    const int end = offsets[node + 1];

    float4 sA0{0.f, 0.f, 0.f, 0.f}, sA1{0.f, 0.f, 0.f, 0.f};
    float4 sB0{0.f, 0.f, 0.f, 0.f}, sB1{0.f, 0.f, 0.f, 0.f};
    const uint4* p = msgs4 + (size_t)beg * 16 + m16;   // 16 uint4 per 256B msg row
    int i = beg;
    for (; i + 3 < end; i += 4, p += 64) {
        const uint4 u0 = p[0];
        const uint4 u1 = p[16];
        const uint4 u2 = p[32];
        const uint4 u3 = p[48];
        sA0.x += bflo(u0.x); sA0.y += bfhi(u0.x); sA0.z += bflo(u0.y); sA0.w += bfhi(u0.y);
        sA1.x += bflo(u0.z); sA1.y += bfhi(u0.z); sA1.z += bflo(u0.w); sA1.w += bfhi(u0.w);
        sB0.x += bflo(u1.x); sB0.y += bfhi(u1.x); sB0.z += bflo(u1.y); sB0.w += bfhi(u1.y);
        sB1.x += bflo(u1.z); sB1.y += bfhi(u1.z); sB1.z += bflo(u1.w); sB1.w += bfhi(u1.w);
        sA0.x += bflo(u2.x); sA0.y += bfhi(u2.x); sA0.z += bflo(u2.y); sA0.w += bfhi(u2.y);
        sA1.x += bflo(u2.z); sA1.y += bfhi(u2.z); sA1.z += bflo(u2.w); sA1.w += bfhi(u2.w);
        sB0.x += bflo(u3.x); sB0.y += bfhi(u3.x); sB0.z += bflo(u3.y); sB0.w += bfhi(u3.y);
        sB1.x += bflo(u3.z); sB1.y += bfhi(u3.z); sB1.z += bflo(u3.w); sB1.w += bfhi(u3.w);
    }
    for (; i < end; ++i, p += 16) {
        const uint4 u = p[0];
        sA0.x += bflo(u.x); sA0.y += bfhi(u.x); sA0.z += bflo(u.y); sA0.w += bfhi(u.y);
        sA1.x += bflo(u.z); sA1.y += bfhi(u.z); sA1.z += bflo(u.w); sA1.w += bfhi(u.w);
    }
    float4 s0, s1;
    s0.x = sA0.x + sB0.x + n0.x; s0.y = sA0.y + sB0.y + n0.y;
    s0.z = sA0.z + sB0.z + n0.z; s0.w = sA0.w + sB0.w + n0.w;
    s1.x = sA1.x + sB1.x + n1.x; s1.y = sA1.y + sB1.y + n1.y;
    s1.z = sA1.z + sB1.z + n1.z; s1.w = sA1.w + sB1.w + n1.w;

    float4* po = (float4*)(out + (size_t)node * ND) + m16 * 2;
    po[0] = s0;
    po[1] = s1;
}

extern "C" void kernel_launch(void* const* d_in, const int* in_sizes, int n_in,
                              void* d_out, int out_size, void* d_ws, size_t ws_size,
                              hipStream_t stream) {
    const float* nf  = (const float*)d_in[0];
    const float* ef  = (const float*)d_in[1];
    const int*  eidx = (const int*)d_in[2];
    const float* We1 = (const float*)d_in[3];
    const float* be1 = (const float*)d_in[4];
    const float* We2 = (const float*)d_in[5];
    const float* be2 = (const float*)d_in[6];
    const float* Wn1 = (const float*)d_in[7];
    const float* bn1 = (const float*)d_in[8];
    const float* Wn2 = (const float*)d_in[9];
    const float* bn2 = (const float*)d_in[10];
    float* out = (float*)d_out;

    char* ws = (char*)d_ws;
    unsigned short* msgs = (unsigned short*)(ws + WS_MSGS);
    unsigned short* pre  = (unsigned short*)(ws + WS_PRE);
    int* pos             = (int*)(ws + WS_POS);
    int* counts          = (int*)(ws + WS_COUNTS);
    int* offsets         = (int*)(ws + WS_OFFSETS);
    short8* wfE          = (short8*)(ws + WS_WFE);
    short8* wfN          = (short8*)(ws + WS_WFN);
    int* wctr            = counts + WCTR_IDX;   // zeroed by the memset below
    (void)ws_size; (void)WS_END;

    hipMemsetAsync(counts, 0, (size_t)COUNTS_PAD * 4, stream);
    wprep<<<19, 256, 0, stream>>>(We1, We2, Wn1, Wn2, wfE, wfN);
    hist_pos<<<(N_EDGES + 255) / 256, 256, 0, stream>>>(eidx, counts, pos);
    scan_kernel<<<1, 1024, 0, stream>>>(counts, offsets);
    node_pre_mfma<<<(N_NODES + 63) / 64, 256, 0, stream>>>(nf, wfN, pre);
    edge_mfma<<<768, 256, 0, stream>>>(
        ef, eidx, pre, pos, offsets, wfE, be1, be2, bn1, bn2, wctr, msgs);
    gather2<<<N_NODES / 16, 256, 0, stream>>>(nf, (const uint4*)msgs, offsets, out);
}